// Round 7
// baseline (124.230 us; speedup 1.0000x reference)
//
#include <hip/hip_runtime.h>

// OPAM_Small_CatPool: B=256, C=512, CI=128, L=150.
// Round 7: independent-block parallelism.
//   prep_all: Wqk=Wq^T Wk split; Wv split; cvec=Wk^T bq
//   k1_vt (grid 512 = b x l-half): v = Wv x + bv (MFMA 3-split) -> vpck u32(hi|lo),
//         t = Wqk v (local j's) -> tT u32, svec, v-part pool partials
//   k2_attn (grid 1280 = i5*256+b, ~74KB LDS, 2 blocks/CU): E = v^T t (3-split,
//         A-rows in LDS, tT strips staged T14-style), local softmax (j-frags
//         {3,3,2,2} cover exactly j<160), PV (vh gathered from L2-resident vpck),
//         att-part pool partials
//   tail_comb: combine partials -> out[:,256:512], dw
//   tail_pwbn: pw = Wp dw^T + batch-stat BN + relu -> out[:,0:256]
// bd/bp dropped (cancel in BN mean subtraction); energy row-constant bias terms
// cancel in softmax; column term kept via svec.

typedef float f32x4  __attribute__((ext_vector_type(4)));
typedef short s16x8  __attribute__((ext_vector_type(8)));
typedef unsigned short BF;

union U8 { s16x8 v; BF u[8]; uint2 d[2]; unsigned w[4]; };

__device__ __forceinline__ BF bfhi(float f) { return (BF)(__float_as_uint(f) >> 16); }
__device__ __forceinline__ float bff(BF h) { return __uint_as_float(((unsigned)h) << 16); }
__device__ __forceinline__ BF bflo(float f, BF hi) { return bfhi(f - bff(hi)); }
__device__ __forceinline__ BF bfrne(float f) {
    unsigned u = __float_as_uint(f);
    u += 0x7fffu + ((u >> 16) & 1u);
    return (BF)(u >> 16);
}
__device__ __forceinline__ s16x8 ld8l(const BF* p) {
    U8 t; t.d[0] = *(const uint2*)p; t.d[1] = *(const uint2*)(p + 4); return t.v;
}
__device__ __forceinline__ void st4(BF* p, BF a, BF b, BF c, BF d) {
    uint2 t; t.x = (unsigned)a | ((unsigned)b << 16);
    t.y = (unsigned)c | ((unsigned)d << 16);
    *(uint2*)p = t;
}
// 8 packed u32 (hi16|lo16) -> hi/lo s16x8 fragments (global or LDS pointer)
__device__ __forceinline__ void ldv8(const unsigned* p, s16x8& hi, s16x8& lo) {
    unsigned u[8];
    *(uint4*)&u[0] = *(const uint4*)p;
    *(uint4*)&u[4] = *(const uint4*)(p + 4);
    U8 H, L;
    #pragma unroll
    for (int e = 0; e < 4; ++e) {
        unsigned a = u[2*e], b2 = u[2*e + 1];
        H.w[e] = (a >> 16) | (b2 & 0xffff0000u);
        L.w[e] = (a & 0xffffu) | (b2 << 16);
    }
    hi = H.v; lo = L.v;
}
__device__ __forceinline__ unsigned packf(float f) {
    BF h = bfhi(f);
    return ((unsigned)h << 16) | (unsigned)bflo(f, h);
}
#define MFMA(a, b, c) __builtin_amdgcn_mfma_f32_16x16x32_bf16(a, b, c, 0, 0, 0)

// ------------------------- prep: Wqk + splits + cvec -------------------------
__global__ __launch_bounds__(256)
void prep_all(const float* __restrict__ Wv, const float* __restrict__ Wq,
              const float* __restrict__ Wk, const float* __restrict__ bq,
              BF* __restrict__ wvh, BF* __restrict__ wvl,
              BF* __restrict__ wqh, BF* __restrict__ wql,
              float* __restrict__ cvec)
{
    __shared__ float qs[128][33], ks_[128][33];
    const int blk = blockIdx.x, tid = threadIdx.x;
    if (blk < 64) {
        int i = blk * 1024 + tid * 4;
        float4 v = *(const float4*)(Wv + i);
        BF h0 = bfhi(v.x), h1 = bfhi(v.y), h2 = bfhi(v.z), h3 = bfhi(v.w);
        st4(&wvh[i], h0, h1, h2, h3);
        st4(&wvl[i], bflo(v.x,h0), bflo(v.y,h1), bflo(v.z,h2), bflo(v.w,h3));
    } else if (blk < 80) {
        int bi = blk - 64;
        int d1_0 = (bi >> 2) * 32, d2_0 = (bi & 3) * 32;
        for (int i = tid; i < 4096; i += 256) {
            int o = i >> 5, c = i & 31;
            qs[o][c]  = Wq[o * 128 + d1_0 + c];
            ks_[o][c] = Wk[o * 128 + d2_0 + c];
        }
        __syncthreads();
        #pragma unroll
        for (int j = 0; j < 4; ++j) {
            int idx = j * 256 + tid;
            int d1 = idx >> 5, d2 = idx & 31;
            float s = 0.f;
            #pragma unroll 8
            for (int o = 0; o < 128; ++o) s = fmaf(qs[o][d1], ks_[o][d2], s);
            BF h = bfhi(s);
            wqh[(d1_0 + d1) * 128 + d2_0 + d2] = h;
            wql[(d1_0 + d1) * 128 + d2_0 + d2] = bflo(s, h);
        }
    } else {
        if (tid < 128) {
            float s = 0.f;
            for (int o = 0; o < 128; ++o) s += bq[o] * Wk[o * 128 + tid];
            cvec[tid] = s;
        }
    }
}

// ------------------------- k1: v + t + svec + v-part partials -------------------------
// grid 512 (b x l-half), 512 thr: 4 compute + 4 stager waves; then 8 waves t-phase
__global__ __launch_bounds__(512, 4)
void k1_vt(const float* __restrict__ x, const BF* __restrict__ wvh,
           const BF* __restrict__ wvl, const float* __restrict__ bv,
           const BF* __restrict__ wqh, const BF* __restrict__ wql,
           const float* __restrict__ cvec, const float* __restrict__ Wd,
           unsigned* __restrict__ vp, unsigned* __restrict__ tT,
           float* __restrict__ svg, float* __restrict__ vpm,
           float* __restrict__ vpd)
{
    __shared__ char smem[42240];
    BF (*xt)[2][80][36] = (BF(*)[2][80][36])smem;      // V staging (23KB)
    unsigned (*vpk)[132] = (unsigned(*)[132])smem;     // overlays xt after V (42.2KB)

    const int bx = blockIdx.x;
    const int b = bx & 255, lh = bx >> 8;
    const int l0 = lh * 80;
    const float* xb = x + (long)b * 76800 + l0;
    const int tid = threadIdx.x, lane = tid & 63, w = tid >> 6;
    const int li = lane & 15, gq = lane >> 4;

    // ================= phase V =================
    if (w < 4) {
        f32x4 acc[5][2];
        #pragma unroll
        for (int mf = 0; mf < 5; ++mf)
            #pragma unroll
            for (int nf = 0; nf < 2; ++nf) acc[mf][nf] = f32x4{0.f,0.f,0.f,0.f};
        s16x8 bh[2], bl[2];
        #pragma unroll
        for (int nf = 0; nf < 2; ++nf) {
            long g = (long)(w*32 + nf*16 + li)*512 + gq*8;
            bh[nf] = *(const s16x8*)(wvh + g);
            bl[nf] = *(const s16x8*)(wvl + g);
        }
        __syncthreads();
        for (int p = 0; p < 16; ++p) {
            s16x8 nbh[2], nbl[2];
            if (p < 15) {
                #pragma unroll
                for (int nf = 0; nf < 2; ++nf) {
                    long g = (long)(w*32 + nf*16 + li)*512 + (p+1)*32 + gq*8;
                    nbh[nf] = *(const s16x8*)(wvh + g);
                    nbl[nf] = *(const s16x8*)(wvl + g);
                }
            }
            const BF (*xh)[36] = xt[p & 1][0];
            const BF (*xl)[36] = xt[p & 1][1];
            #pragma unroll
            for (int mf = 0; mf < 5; ++mf) {
                int row = mf*16 + li;
                s16x8 ah = ld8l(&xh[row][gq*8]);
                s16x8 al = ld8l(&xl[row][gq*8]);
                #pragma unroll
                for (int nf = 0; nf < 2; ++nf) {
                    acc[mf][nf] = MFMA(al, bh[nf], acc[mf][nf]);
                    acc[mf][nf] = MFMA(ah, bl[nf], acc[mf][nf]);
                    acc[mf][nf] = MFMA(ah, bh[nf], acc[mf][nf]);
                }
            }
            if (p < 15) {
                #pragma unroll
                for (int nf = 0; nf < 2; ++nf) { bh[nf] = nbh[nf]; bl[nf] = nbl[nf]; }
            }
            __syncthreads();
        }
        // epilogue: +bv, pack, write vpck global + vpk LDS, v-part partials
        #pragma unroll
        for (int nf = 0; nf < 2; ++nf) {
            int c = w*32 + nf*16 + li;
            float bvv = bv[c];
            float mx = -3.4e38f, dt = 0.f;
            #pragma unroll
            for (int mf = 0; mf < 5; ++mf)
                #pragma unroll
                for (int r = 0; r < 4; ++r) {
                    int ll = mf*16 + gq*4 + r;
                    float f = acc[mf][nf][r] + bvv;
                    unsigned pk = packf(f);
                    vp[((long)b*160 + l0 + ll)*128 + c] = pk;
                    vpk[ll][c] = pk;
                    if (l0 + ll < 150) {
                        mx = fmaxf(mx, f);
                        dt = fmaf(f, Wd[(128 + c)*150 + l0 + ll], dt);
                    }
                }
            mx = fmaxf(mx, __shfl_xor(mx, 16)); dt += __shfl_xor(dt, 16);
            mx = fmaxf(mx, __shfl_xor(mx, 32)); dt += __shfl_xor(dt, 32);
            if (gq == 0) {
                vpm[((long)lh*256 + b)*128 + c] = mx;
                vpd[((long)lh*256 + b)*128 + c] = dt;
            }
        }
    } else {
        const int sw = w - 4;
        const int bound = (lh == 0) ? 16 : 6;
        float cur[2][8];
        auto ldchunk = [&](int p) {
            #pragma unroll
            for (int cc = 0; cc < 8; ++cc) {
                int ch = p*32 + sw*8 + cc;
                cur[0][cc] = xb[ch*150 + lane];
                cur[1][cc] = (lane < bound) ? xb[ch*150 + 64 + lane] : 0.f;
            }
        };
        auto wrchunk = [&](int buf) {
            #pragma unroll
            for (int g2 = 0; g2 < 2; ++g2) {
                BF h0 = bfhi(cur[0][g2*4+0]), h1 = bfhi(cur[0][g2*4+1]);
                BF h2 = bfhi(cur[0][g2*4+2]), h3 = bfhi(cur[0][g2*4+3]);
                st4(&xt[buf][0][lane][sw*8 + g2*4], h0, h1, h2, h3);
                st4(&xt[buf][1][lane][sw*8 + g2*4],
                    bflo(cur[0][g2*4+0],h0), bflo(cur[0][g2*4+1],h1),
                    bflo(cur[0][g2*4+2],h2), bflo(cur[0][g2*4+3],h3));
                if (lane < 16) {
                    BF k0 = bfhi(cur[1][g2*4+0]), k1 = bfhi(cur[1][g2*4+1]);
                    BF k2 = bfhi(cur[1][g2*4+2]), k3 = bfhi(cur[1][g2*4+3]);
                    st4(&xt[buf][0][64 + lane][sw*8 + g2*4], k0, k1, k2, k3);
                    st4(&xt[buf][1][64 + lane][sw*8 + g2*4],
                        bflo(cur[1][g2*4+0],k0), bflo(cur[1][g2*4+1],k1),
                        bflo(cur[1][g2*4+2],k2), bflo(cur[1][g2*4+3],k3));
                }
            }
        };
        ldchunk(0); wrchunk(0); ldchunk(1);
        __syncthreads();
        for (int p = 0; p < 16; ++p) {
            if (p < 15) {
                wrchunk((p + 1) & 1);
                if (p < 14) ldchunk(p + 2);
            }
            __syncthreads();
        }
    }
    __syncthreads();   // vpk ready block-wide

    // ================= svec (this l-half) =================
    if (tid < 160) {
        int j = tid >> 1, hf = tid & 1;
        float s = 0.f;
        #pragma unroll 8
        for (int d2 = hf*64; d2 < hf*64 + 64; ++d2)
            s += cvec[d2] * bff((BF)(vpk[j][d2] >> 16));
        s += __shfl_xor(s, 1);
        if (hf == 0) svg[(long)b*160 + l0 + j] = s;
    }

    // ================= t = Wqk v (local j-half) =================
    {
        const int c0 = w * 16;
        f32x4 acc2[5];
        #pragma unroll
        for (int i = 0; i < 5; ++i) acc2[i] = f32x4{0.f,0.f,0.f,0.f};
        #pragma unroll
        for (int kd = 0; kd < 4; ++kd) {
            long ga = (long)(c0 + li)*128 + kd*32 + gq*8;
            s16x8 ah = *(const s16x8*)(wqh + ga);
            s16x8 al = *(const s16x8*)(wql + ga);
            #pragma unroll
            for (int jf = 0; jf < 5; ++jf) {
                s16x8 vh_, vl_;
                ldv8(&vpk[jf*16 + li][kd*32 + gq*8], vh_, vl_);
                acc2[jf] = MFMA(ah, vl_, acc2[jf]);
                acc2[jf] = MFMA(al, vh_, acc2[jf]);
                acc2[jf] = MFMA(ah, vh_, acc2[jf]);
            }
        }
        #pragma unroll
        for (int jf = 0; jf < 5; ++jf) {
            unsigned pk[4];
            #pragma unroll
            for (int r = 0; r < 4; ++r) pk[r] = packf(acc2[jf][r]);
            *(uint4*)&tT[((long)b*160 + l0 + jf*16 + li)*128 + c0 + gq*4] = *(uint4*)pk;
        }
    }
}

// ------------------------- k2: attention i-block -------------------------
// grid 1280: bid = i5*256 + b (XCD affinity: bid%8 == b%8). 512 thr.
// LDS: vAh 8448 | vAl 8448 | tst 2*160*36*4=46080 | P 32*172*2=11008 | smax 512 | ssum 512
__global__ __launch_bounds__(512, 4)
void k2_attn(const unsigned* __restrict__ vp, const unsigned* __restrict__ tT,
             const float* __restrict__ svg, const float* __restrict__ gammap,
             const float* __restrict__ Wd,
             float* __restrict__ pmax_g, float* __restrict__ pdot_g)
{
    __shared__ char smem[75008];
    BF (*vAh)[132] = (BF(*)[132])smem;
    BF (*vAl)[132] = (BF(*)[132])(smem + 8448);
    unsigned (*tst)[160][36] = (unsigned(*)[160][36])(smem + 16896);
    BF (*P)[172] = (BF(*)[172])(smem + 62976);
    float* smax = (float*)(smem + 73984);   // [4][32]
    float* ssum = smax + 128;               // [4][32]

    const int bid = blockIdx.x;
    const int b = bid & 255, i5 = bid >> 8;
    const int i0 = i5 * 32;
    const unsigned* vb = vp + (long)b * 20480;
    const unsigned* tb = tT + (long)b * 20480;
    const int tid = threadIdx.x;
    const int lane = tid & 63, w = tid >> 6;
    const int li = lane & 15, gq = lane >> 4;
    const float gamma = gammap[0];

    const int it = w >> 2, jw = w & 3;
    const int jbase = (jw < 2) ? jw*48 : 96 + (jw - 2)*32;
    const int nfcnt = (jw < 2) ? 3 : 2;

    // ---- load vA rows i0..i0+31 (unpack hi/lo -> LDS) ----
    {
        int row = tid >> 4, c8 = (tid & 15) * 8;
        const unsigned* src = vb + ((long)(i0 + row))*128 + c8;
        unsigned u[8];
        *(uint4*)&u[0] = *(const uint4*)src;
        *(uint4*)&u[4] = *(const uint4*)(src + 4);
        BF hh[8], ll_[8];
        #pragma unroll
        for (int e = 0; e < 8; ++e) { hh[e] = (BF)(u[e] >> 16); ll_[e] = (BF)(u[e] & 0xffffu); }
        st4(&vAh[row][c8], hh[0], hh[1], hh[2], hh[3]);
        st4(&vAh[row][c8+4], hh[4], hh[5], hh[6], hh[7]);
        st4(&vAl[row][c8], ll_[0], ll_[1], ll_[2], ll_[3]);
        st4(&vAl[row][c8+4], ll_[4], ll_[5], ll_[6], ll_[7]);
    }

    // ---- tT strip staging (320 threads), T14 issue-early/write-late ----
    uint4 sreg[4];
    auto ldstrip = [&](int s) {
        if (tid < 320) {
            int j = tid >> 1, h = tid & 1;
            const uint4* src = (const uint4*)(tb + (long)j*128 + s*32 + h*16);
            sreg[0] = src[0]; sreg[1] = src[1]; sreg[2] = src[2]; sreg[3] = src[3];
        }
    };
    auto wrstrip = [&](int buf) {
        if (tid < 320) {
            int j = tid >> 1, h = tid & 1;
            unsigned* dst = &tst[buf][j][h*16];
            *(uint4*)(dst + 0)  = sreg[0];
            *(uint4*)(dst + 4)  = sreg[1];
            *(uint4*)(dst + 8)  = sreg[2];
            *(uint4*)(dst + 12) = sreg[3];
        }
    };

    f32x4 eacc[3];
    #pragma unroll
    for (int i = 0; i < 3; ++i) eacc[i] = f32x4{0.f,0.f,0.f,0.f};

    ldstrip(0); wrstrip(0); ldstrip(1);
    __syncthreads();

    // ---- E = v^T t over 4 c-strips ----
    for (int s = 0; s < 4; ++s) {
        if (s < 3) wrstrip((s + 1) & 1);
        if (s < 2) ldstrip(s + 2);
        const int buf = s & 1;
        s16x8 ah = ld8l(&vAh[it*16 + li][s*32 + gq*8]);
        s16x8 al = ld8l(&vAl[it*16 + li][s*32 + gq*8]);
        for (int nf = 0; nf < nfcnt; ++nf) {
            int jr = jbase + nf*16 + li;
            s16x8 bh, bl;
            ldv8(&tst[buf][jr][gq*8], bh, bl);
            eacc[nf] = MFMA(ah, bl, eacc[nf]);
            eacc[nf] = MFMA(al, bh, eacc[nf]);
            eacc[nf] = MFMA(ah, bh, eacc[nf]);
        }
        __syncthreads();
    }

    // ---- softmax over j (rows i0..i0+31), cross-jw via LDS ----
    for (int nf = 0; nf < nfcnt; ++nf) {
        int j = jbase + nf*16 + li;
        float sv = svg[(long)b*160 + j];
        #pragma unroll
        for (int r = 0; r < 4; ++r) eacc[nf][r] += sv;
    }
    #pragma unroll
    for (int r = 0; r < 4; ++r) {
        int iloc = it*16 + gq*4 + r;
        float m = -3.4e38f;
        for (int nf = 0; nf < nfcnt; ++nf) {
            int j = jbase + nf*16 + li;
            if (j < 150) m = fmaxf(m, eacc[nf][r]);
        }
        #pragma unroll
        for (int o = 1; o < 16; o <<= 1) m = fmaxf(m, __shfl_xor(m, o));
        if (li == 0) smax[jw*32 + iloc] = m;
    }
    __syncthreads();
    #pragma unroll
    for (int r = 0; r < 4; ++r) {
        int iloc = it*16 + gq*4 + r;
        float gm = fmaxf(fmaxf(smax[iloc], smax[32 + iloc]),
                         fmaxf(smax[64 + iloc], smax[96 + iloc]));
        float rs_ = 0.f;
        for (int nf = 0; nf < nfcnt; ++nf) {
            int j = jbase + nf*16 + li;
            float e = (j < 150) ? __expf(eacc[nf][r] - gm) : 0.f;
            eacc[nf][r] = e;
            rs_ += e;
        }
        #pragma unroll
        for (int o = 1; o < 16; o <<= 1) rs_ += __shfl_xor(rs_, o);
        if (li == 0) ssum[jw*32 + iloc] = rs_;
    }
    __syncthreads();
    #pragma unroll
    for (int r = 0; r < 4; ++r) {
        int iloc = it*16 + gq*4 + r;
        float inv = 1.f / (ssum[iloc] + ssum[32 + iloc] + ssum[64 + iloc] + ssum[96 + iloc]);
        for (int nf = 0; nf < nfcnt; ++nf) {
            int j = jbase + nf*16 + li;
            P[iloc][j] = bfrne(eacc[nf][r] * inv);
        }
    }
    __syncthreads();

    // ---- PV + fused partial reduce ----
    {
        const int pc = w;   // c-16 tile
        f32x4 oacc[2];
        oacc[0] = f32x4{0.f,0.f,0.f,0.f};
        oacc[1] = f32x4{0.f,0.f,0.f,0.f};
        #pragma unroll
        for (int ks = 0; ks < 5; ++ks) {
            U8 t;
            #pragma unroll
            for (int e = 0; e < 8; ++e)
                t.u[e] = (BF)(vb[((long)(ks*32 + gq*8 + e))*128 + pc*16 + li] >> 16);
            #pragma unroll
            for (int nf2 = 0; nf2 < 2; ++nf2) {
                s16x8 bp = ld8l(&P[nf2*16 + li][ks*32 + gq*8]);
                oacc[nf2] = MFMA(t.v, bp, oacc[nf2]);
            }
        }
        #pragma unroll
        for (int r = 0; r < 4; ++r) {
            int c = pc*16 + gq*4 + r;
            float mx = -3.4e38f, dt = 0.f;
            #pragma unroll
            for (int nf2 = 0; nf2 < 2; ++nf2) {
                int l = i0 + nf2*16 + li;
                if (l < 150) {
                    float val = gamma * oacc[nf2][r];
                    mx = fmaxf(mx, val);
                    dt = fmaf(val, Wd[c*150 + l], dt);
                }
            }
            #pragma unroll
            for (int o = 1; o < 16; o <<= 1) {
                mx = fmaxf(mx, __shfl_xor(mx, o));
                dt += __shfl_xor(dt, o);
            }
            if (li == 0) {
                pmax_g[((long)i5*256 + b)*128 + c] = mx;
                pdot_g[((long)i5*256 + b)*128 + c] = dt;
            }
        }
    }
}

// ------------------------- tail: combine partials -------------------------
__global__ __launch_bounds__(256)
void tail_comb(const float* __restrict__ pmax_g, const float* __restrict__ pdot_g,
               const float* __restrict__ vpm, const float* __restrict__ vpd,
               float* __restrict__ dw, float* __restrict__ out)
{
    const int b = blockIdx.x, ch = threadIdx.x;
    if (ch < 128) {
        float mx = -3.4e38f, dt = 0.f;
        #pragma unroll
        for (int i5 = 0; i5 < 5; ++i5) {
            mx = fmaxf(mx, pmax_g[((long)i5*256 + b)*128 + ch]);
            dt += pdot_g[((long)i5*256 + b)*128 + ch];
        }
        out[(long)b*512 + 256 + ch] = mx;
        dw[b*256 + ch] = dt;
    } else {
        int c2 = ch - 128;
        float m0 = vpm[(long)b*128 + c2], m1 = vpm[(long)(256 + b)*128 + c2];
        out[(long)b*512 + 256 + ch] = fmaxf(m0, m1);
        dw[b*256 + ch] = vpd[(long)b*128 + c2] + vpd[(long)(256 + b)*128 + c2];
    }
}

// ------------------------- tail: pw GEMM + BN + relu -------------------------
__global__ __launch_bounds__(256)
void tail_pwbn(const float* __restrict__ dw, const float* __restrict__ Wp,
               const float* __restrict__ bn_g, const float* __restrict__ bn_b,
               float* __restrict__ out)
{
    __shared__ float wp_s[256];
    __shared__ float rs[4], rs2[4];
    const int o = blockIdx.x, t = threadIdx.x;
    const int lane = t & 63, w = t >> 6;
    wp_s[t] = Wp[o * 256 + t];
    __syncthreads();
    const float4* dr = (const float4*)(dw + (long)t * 256);
    float acc = 0.f;
    #pragma unroll 8
    for (int i = 0; i < 64; ++i) {
        float4 d4 = dr[i];
        acc = fmaf(d4.x, wp_s[i*4+0], acc);
        acc = fmaf(d4.y, wp_s[i*4+1], acc);
        acc = fmaf(d4.z, wp_s[i*4+2], acc);
        acc = fmaf(d4.w, wp_s[i*4+3], acc);
    }
    float s = acc, s2 = acc * acc;
    #pragma unroll
    for (int d = 1; d < 64; d <<= 1) { s += __shfl_xor(s, d); s2 += __shfl_xor(s2, d); }
    if (lane == 0) { rs[w] = s; rs2[w] = s2; }
    __syncthreads();
    float S  = rs[0] + rs[1] + rs[2] + rs[3];
    float S2 = rs2[0] + rs2[1] + rs2[2] + rs2[3];
    float mean = S * (1.f/256.f);
    float var  = S2 * (1.f/256.f) - mean * mean;
    float sc = rsqrtf(var + 1e-5f) * bn_g[o];
    float sh = bn_b[o] - mean * sc;
    out[(long)t * 512 + o] = fmaxf(fmaf(acc, sc, sh), 0.f);
}

extern "C" void kernel_launch(void* const* d_in, const int* in_sizes, int n_in,
                              void* d_out, int out_size, void* d_ws, size_t ws_size,
                              hipStream_t stream)
{
    (void)in_sizes; (void)n_in; (void)out_size; (void)ws_size;
    const float* x    = (const float*)d_in[0];
    const float* Wv   = (const float*)d_in[1];
    const float* bv   = (const float*)d_in[2];
    const float* Wq   = (const float*)d_in[3];
    const float* bq   = (const float*)d_in[4];
    const float* Wk   = (const float*)d_in[5];
    const float* bk   = (const float*)d_in[6];  (void)bk; // row-const: cancels in softmax
    const float* gam  = (const float*)d_in[7];
    const float* Wd   = (const float*)d_in[8];
    // d_in[9] = bd, d_in[11] = bp: BN-invariant, unused.
    const float* Wp   = (const float*)d_in[10];
    const float* bn_g = (const float*)d_in[12];
    const float* bn_b = (const float*)d_in[13];
    float* out = (float*)d_out;

    char* wsb = (char*)d_ws;
    BF* wvh   = (BF*)wsb;                         // 131072
    BF* wvl   = (BF*)(wsb + 131072);              // 131072
    BF* wqh   = (BF*)(wsb + 262144);              // 32768
    BF* wql   = (BF*)(wsb + 294912);              // 32768
    float* cvec = (float*)(wsb + 327680);         // 512
    unsigned* vpck = (unsigned*)(wsb + 328192);   // 20971520
    unsigned* tT   = (unsigned*)(wsb + 21299712); // 20971520
    float* svg  = (float*)(wsb + 42271232);       // 163840
    float* vpm  = (float*)(wsb + 42435072);       // 262144
    float* vpd  = (float*)(wsb + 42697216);       // 262144
    float* pmax_g = (float*)(wsb + 42959360);     // 655360
    float* pdot_g = (float*)(wsb + 43614720);     // 655360
    float* dw   = (float*)(wsb + 44270080);       // 262144

    prep_all<<<81, 256, 0, stream>>>(Wv, Wq, Wk, bq, wvh, wvl, wqh, wql, cvec);
    k1_vt<<<512, 512, 0, stream>>>(x, wvh, wvl, bv, wqh, wql, cvec, Wd,
                                   vpck, tT, svg, vpm, vpd);
    k2_attn<<<1280, 512, 0, stream>>>(vpck, tT, svg, gam, Wd, pmax_g, pdot_g);
    tail_comb<<<256, 256, 0, stream>>>(pmax_g, pdot_g, vpm, vpd, dw, out);
    tail_pwbn<<<256, 256, 0, stream>>>(dw, Wp, bn_g, bn_b, out);
}

// Round 8
// 88.845 us; speedup vs baseline: 1.3983x; 1.3983x over previous
//
#include <hip/hip_runtime.h>

// OPAM_Small_CatPool: B=256, C=512, CI=128, L=150.
// Round 8: r5 fused structure + LDS-instruction diet.
//   - xt stride 40 (16B rows) -> single ds_read_b128 A-frags in V
//   - ts packed u32 stride 44 -> half the writes, b128 reads + unpack
//   - one-barrier softmax (local max/sum, fold correction into P scale)
//   - vectorized svec, s_setprio around role-diverse MFMA clusters
//   - no ts pad zeroing (masked by j<150 branch; NaN-safe)
// bd/bp dropped (cancel in BN mean subtraction); energy row-constant bias terms
// cancel in softmax; column term kept via svec.

typedef float f32x4  __attribute__((ext_vector_type(4)));
typedef float f32x16 __attribute__((ext_vector_type(16)));
typedef short s16x8  __attribute__((ext_vector_type(8)));
typedef unsigned short BF;

union U8 { s16x8 v; BF u[8]; uint2 d[2]; unsigned w[4]; };

__device__ __forceinline__ BF bfhi(float f) { return (BF)(__float_as_uint(f) >> 16); }
__device__ __forceinline__ float bff(BF h) { return __uint_as_float(((unsigned)h) << 16); }
__device__ __forceinline__ BF bflo(float f, BF hi) { return bfhi(f - bff(hi)); }
__device__ __forceinline__ BF bfrne(float f) {
    unsigned u = __float_as_uint(f);
    u += 0x7fffu + ((u >> 16) & 1u);
    return (BF)(u >> 16);
}
__device__ __forceinline__ s16x8 ld8l(const BF* p) {   // 8B-aligned (b64 pair)
    U8 t; t.d[0] = *(const uint2*)p; t.d[1] = *(const uint2*)(p + 4); return t.v;
}
__device__ __forceinline__ void st4(BF* p, BF a, BF b, BF c, BF d) {
    uint2 t; t.x = (unsigned)a | ((unsigned)b << 16);
    t.y = (unsigned)c | ((unsigned)d << 16);
    *(uint2*)p = t;
}
// 8 packed u32 (hi16|lo16), 16B-aligned -> hi/lo s16x8
__device__ __forceinline__ void ldv8(const unsigned* p, s16x8& hi, s16x8& lo) {
    unsigned u[8];
    *(uint4*)&u[0] = *(const uint4*)p;
    *(uint4*)&u[4] = *(const uint4*)(p + 4);
    U8 H, L;
    #pragma unroll
    for (int e = 0; e < 4; ++e) {
        unsigned a = u[2*e], b2 = u[2*e + 1];
        H.w[e] = (a >> 16) | (b2 & 0xffff0000u);
        L.w[e] = (a & 0xffffu) | (b2 << 16);
    }
    hi = H.v; lo = L.v;
}
__device__ __forceinline__ unsigned packf(float f) {
    BF h = bfhi(f);
    return ((unsigned)h << 16) | (unsigned)bflo(f, h);
}
#define MFMA(a, b, c)   __builtin_amdgcn_mfma_f32_16x16x32_bf16(a, b, c, 0, 0, 0)
#define MFMA32(a, b, c) __builtin_amdgcn_mfma_f32_32x32x16_bf16(a, b, c, 0, 0, 0)

// ------------------------- prep: Wqk + splits + cvec -------------------------
__global__ __launch_bounds__(256)
void prep_all(const float* __restrict__ Wv, const float* __restrict__ Wq,
              const float* __restrict__ Wk, const float* __restrict__ bq,
              BF* __restrict__ wvh, BF* __restrict__ wvl,
              BF* __restrict__ wqh, BF* __restrict__ wql,
              float* __restrict__ cvec)
{
    __shared__ float qs[128][33], ks_[128][33];
    const int blk = blockIdx.x, tid = threadIdx.x;
    if (blk < 64) {
        int i = blk * 1024 + tid * 4;
        float4 v = *(const float4*)(Wv + i);
        BF h0 = bfhi(v.x), h1 = bfhi(v.y), h2 = bfhi(v.z), h3 = bfhi(v.w);
        st4(&wvh[i], h0, h1, h2, h3);
        st4(&wvl[i], bflo(v.x,h0), bflo(v.y,h1), bflo(v.z,h2), bflo(v.w,h3));
    } else if (blk < 80) {
        int bi = blk - 64;
        int d1_0 = (bi >> 2) * 32, d2_0 = (bi & 3) * 32;
        for (int i = tid; i < 4096; i += 256) {
            int o = i >> 5, c = i & 31;
            qs[o][c]  = Wq[o * 128 + d1_0 + c];
            ks_[o][c] = Wk[o * 128 + d2_0 + c];
        }
        __syncthreads();
        #pragma unroll
        for (int j = 0; j < 4; ++j) {
            int idx = j * 256 + tid;
            int d1 = idx >> 5, d2 = idx & 31;
            float s = 0.f;
            #pragma unroll 8
            for (int o = 0; o < 128; ++o) s = fmaf(qs[o][d1], ks_[o][d2], s);
            BF h = bfhi(s);
            wqh[(d1_0 + d1) * 128 + d2_0 + d2] = h;
            wql[(d1_0 + d1) * 128 + d2_0 + d2] = bflo(s, h);
        }
    } else {
        if (tid < 128) {
            float s = 0.f;
            for (int o = 0; o < 128; ++o) s += bq[o] * Wk[o * 128 + tid];
            cvec[tid] = s;
        }
    }
}

// ------------------------- fused: v-GEMM + attention + reduce -------------------------
// grid 256 (1/batch), 1024 thr (16 waves, 4 waves/SIMD)
__global__ __launch_bounds__(1024, 4)
void fused_attn(const float* __restrict__ x, const BF* __restrict__ wvh,
                const BF* __restrict__ wvl, const float* __restrict__ bv,
                const BF* __restrict__ wqh, const BF* __restrict__ wql,
                const float* __restrict__ cvec, const float* __restrict__ gammap,
                const float* __restrict__ Wd, float* __restrict__ dw,
                float* __restrict__ out)
{
    __shared__ char smem[161792];
    BF (*vh)[140] = (BF(*)[140])smem;                          // [160][140] @0
    BF (*vl)[140] = (BF(*)[140])(smem + 44800);                // @44800
    BF (*xt)[2][160][40] = (BF(*)[2][160][40])(smem + 89600);  // V staging (51200B)
    unsigned (*ts32)[192][44] = (unsigned(*)[192][44])(smem + 89600); // E strips (67584B)
    BF (*P)[168] = (BF(*)[168])(smem + 44800);                 // overlays vl+ts head
    float* mg   = (float*)(smem + 157184);                     // [3][160]; later pmax[2][128]
    float* sg   = (float*)(smem + 159104);                     // [3][160]; later pdot[2][128]
    float* svec = (float*)(smem + 161024);                     // [192] (160 valid)

    const int b = blockIdx.x;
    const float* xb = x + (long)b * 76800;
    const int tid = threadIdx.x;
    const int lane = tid & 63, w = tid >> 6;
    const int li = lane & 15, gq = lane >> 4;
    const float gamma = gammap[0];

    // ================= phase V: v = Wv x + bv (8 compute + 8 stager waves) =========
    if (w < 8) {
        const int wm = w & 1, wn = w >> 1;
        f32x4 acc[5][2];
        #pragma unroll
        for (int mf = 0; mf < 5; ++mf)
            #pragma unroll
            for (int nf = 0; nf < 2; ++nf) acc[mf][nf] = f32x4{0.f,0.f,0.f,0.f};
        s16x8 bh[2], bl[2];
        #pragma unroll
        for (int nf = 0; nf < 2; ++nf) {
            long g = (long)(wn*32 + nf*16 + li)*512 + gq*8;
            bh[nf] = *(const s16x8*)(wvh + g);
            bl[nf] = *(const s16x8*)(wvl + g);
        }
        __syncthreads();
        for (int p = 0; p < 16; ++p) {
            s16x8 nbh[2], nbl[2];
            if (p < 15) {
                #pragma unroll
                for (int nf = 0; nf < 2; ++nf) {
                    long g = (long)(wn*32 + nf*16 + li)*512 + (p+1)*32 + gq*8;
                    nbh[nf] = *(const s16x8*)(wvh + g);
                    nbl[nf] = *(const s16x8*)(wvl + g);
                }
            }
            const BF (*xh)[40]  = xt[p & 1][0];
            const BF (*xl2)[40] = xt[p & 1][1];
            __builtin_amdgcn_s_setprio(1);
            #pragma unroll
            for (int mf = 0; mf < 5; ++mf) {
                int row = wm*80 + mf*16 + li;
                s16x8 ah = *(const s16x8*)&xh[row][gq*8];    // single b128
                s16x8 al = *(const s16x8*)&xl2[row][gq*8];
                #pragma unroll
                for (int nf = 0; nf < 2; ++nf) {
                    acc[mf][nf] = MFMA(al, bh[nf], acc[mf][nf]);
                    acc[mf][nf] = MFMA(ah, bl[nf], acc[mf][nf]);
                    acc[mf][nf] = MFMA(ah, bh[nf], acc[mf][nf]);
                }
            }
            __builtin_amdgcn_s_setprio(0);
            if (p < 15) {
                #pragma unroll
                for (int nf = 0; nf < 2; ++nf) { bh[nf] = nbh[nf]; bl[nf] = nbl[nf]; }
            }
            __syncthreads();
        }
        #pragma unroll
        for (int nf = 0; nf < 2; ++nf) {
            int c = wn*32 + nf*16 + li;
            float bvv = bv[c];
            #pragma unroll
            for (int mf = 0; mf < 5; ++mf)
                #pragma unroll
                for (int r = 0; r < 4; ++r) {
                    int l = wm*80 + mf*16 + gq*4 + r;
                    float f = acc[mf][nf][r] + bvv;
                    BF h = bfhi(f);
                    vh[l][c] = h;
                    vl[l][c] = bflo(f, h);
                }
        }
    } else {
        const int sw = w - 8;
        float cur[3][4];
        auto ldchunk = [&](int p) {
            #pragma unroll
            for (int it = 0; it < 3; ++it) {
                int l = it*64 + lane;
                #pragma unroll
                for (int cc = 0; cc < 4; ++cc)
                    cur[it][cc] = (l < 150) ? xb[(p*32 + sw*4 + cc)*150 + l] : 0.f;
            }
        };
        auto wrchunk = [&](int buf) {
            #pragma unroll
            for (int it = 0; it < 3; ++it) {
                int l = it*64 + lane;
                if (l < 160) {
                    BF h0=bfhi(cur[it][0]), h1=bfhi(cur[it][1]);
                    BF h2=bfhi(cur[it][2]), h3=bfhi(cur[it][3]);
                    st4(&xt[buf][0][l][sw*4], h0, h1, h2, h3);
                    st4(&xt[buf][1][l][sw*4], bflo(cur[it][0],h0), bflo(cur[it][1],h1),
                                              bflo(cur[it][2],h2), bflo(cur[it][3],h3));
                }
            }
        };
        ldchunk(0); wrchunk(0); ldchunk(1);
        __syncthreads();
        for (int p = 0; p < 16; ++p) {
            if (p < 15) {
                wrchunk((p + 1) & 1);
                if (p < 14) ldchunk(p + 2);
            }
            __syncthreads();
        }
    }
    __syncthreads();   // vh/vl ready block-wide

    // ================= phase E: t = Wqk v (32x32) || svec ; E = v^T t ==========
    f32x4 eacc[2][4];
    #pragma unroll
    for (int a = 0; a < 2; ++a)
        #pragma unroll
        for (int b2 = 0; b2 < 4; ++b2) eacc[a][b2] = f32x4{0.f,0.f,0.f,0.f};
    const int iw = w / 3, jw = w % 3;         // eaccum: i-32-block(5), j-64-block(3); w==15 idle
    const int l31 = lane & 31, hi5 = lane >> 5;

    for (int pr = 0; pr < 2; ++pr) {
        if (w < 10) {   // tgemm32: strips 2pr+s2; tiles (s2 2)x(jt 5)
            const int s2 = w / 5, jt = w % 5;
            const int ss = pr*2 + s2;
            f32x16 tacc;
            #pragma unroll
            for (int r = 0; r < 16; ++r) tacc[r] = 0.f;
            const int cg2 = ss*32 + l31;
            const int jr0 = jt*32 + l31;
            __builtin_amdgcn_s_setprio(1);
            #pragma unroll
            for (int kc = 0; kc < 8; ++kc) {
                int kof = kc*16 + hi5*8;
                s16x8 bh = *(const s16x8*)(wqh + (long)cg2*128 + kof);
                s16x8 bl = *(const s16x8*)(wql + (long)cg2*128 + kof);
                s16x8 ah = ld8l(&vh[jr0][kof]);
                s16x8 al = ld8l(&vl[jr0][kof]);
                tacc = MFMA32(al, bh, tacc);
                tacc = MFMA32(ah, bl, tacc);
                tacc = MFMA32(ah, bh, tacc);
            }
            __builtin_amdgcn_s_setprio(0);
            #pragma unroll
            for (int r = 0; r < 16; ++r) {
                int j = jt*32 + (r & 3) + 8*(r >> 2) + 4*hi5;
                ts32[s2][j][l31] = packf(tacc[r]);
            }
        } else if (pr == 0) {                 // svec (threads 640..799), vectorized
            int t2 = tid - 640;
            if (t2 < 160) {
                float s = 0.f;
                #pragma unroll
                for (int k = 0; k < 16; ++k) {
                    U8 t; t.v = ld8l(&vh[t2][k*8]);
                    #pragma unroll
                    for (int e = 0; e < 8; ++e)
                        s = fmaf(bff(t.u[e]), cvec[k*8 + e], s);
                }
                svec[t2] = s;
            }
        }
        __syncthreads();
        if (w < 15) {   // eaccum both strips of the pair
            #pragma unroll
            for (int s2 = 0; s2 < 2; ++s2) {
                int scol = (pr*2 + s2)*32 + gq*8;
                s16x8 ah[2], al[2];
                #pragma unroll
                for (int mf2 = 0; mf2 < 2; ++mf2) {
                    int row = iw*32 + mf2*16 + li;
                    ah[mf2] = ld8l(&vh[row][scol]);
                    al[mf2] = ld8l(&vl[row][scol]);
                }
                #pragma unroll
                for (int nf = 0; nf < 4; ++nf) {
                    int jr = jw*64 + nf*16 + li;
                    s16x8 bh, bl;
                    ldv8(&ts32[s2][jr][gq*8], bh, bl);
                    #pragma unroll
                    for (int mf2 = 0; mf2 < 2; ++mf2) {
                        eacc[mf2][nf] = MFMA(ah[mf2], bh, eacc[mf2][nf]);
                        eacc[mf2][nf] = MFMA(ah[mf2], bl, eacc[mf2][nf]);
                        eacc[mf2][nf] = MFMA(al[mf2], bh, eacc[mf2][nf]);
                    }
                }
            }
        }
        __syncthreads();
    }

    // ================= softmax over j (one cross-wave barrier) =================
    if (w < 15) {
        #pragma unroll
        for (int nf = 0; nf < 4; ++nf) {
            int j = jw*64 + nf*16 + li;                 // j<192: svec[160..191] garbage, masked below
            float sv = svec[j];
            #pragma unroll
            for (int mf2 = 0; mf2 < 2; ++mf2)
                #pragma unroll
                for (int r = 0; r < 4; ++r)
                    eacc[mf2][nf][r] += sv;
        }
        #pragma unroll
        for (int mf2 = 0; mf2 < 2; ++mf2)
            #pragma unroll
            for (int r = 0; r < 4; ++r) {
                int i = iw*32 + mf2*16 + gq*4 + r;
                float m = -3.4e38f;
                #pragma unroll
                for (int nf = 0; nf < 4; ++nf) {
                    int j = jw*64 + nf*16 + li;
                    if (j < 150) m = fmaxf(m, eacc[mf2][nf][r]);
                }
                #pragma unroll
                for (int o = 1; o < 16; o <<= 1) m = fmaxf(m, __shfl_xor(m, o));
                float rs_ = 0.f;
                #pragma unroll
                for (int nf = 0; nf < 4; ++nf) {
                    int j = jw*64 + nf*16 + li;
                    float e = (j < 150) ? __expf(eacc[mf2][nf][r] - m) : 0.f;
                    eacc[mf2][nf][r] = e;
                    rs_ += e;
                }
                #pragma unroll
                for (int o = 1; o < 16; o <<= 1) rs_ += __shfl_xor(rs_, o);
                if (li == 0) { mg[jw*160 + i] = m; sg[jw*160 + i] = rs_; }
            }
    }
    __syncthreads();
    if (w < 15) {
        #pragma unroll
        for (int mf2 = 0; mf2 < 2; ++mf2)
            #pragma unroll
            for (int r = 0; r < 4; ++r) {
                int i = iw*32 + mf2*16 + gq*4 + r;
                float m0 = mg[i], m1 = mg[160 + i], m2 = mg[320 + i];
                float M = fmaxf(fmaxf(m0, m1), m2);
                float S = fmaf(sg[i], __expf(m0 - M),
                          fmaf(sg[160 + i], __expf(m1 - M),
                               sg[320 + i] * __expf(m2 - M)));
                float scale = __expf(mg[jw*160 + i] - M) / S;
                #pragma unroll
                for (int nf = 0; nf < 4; ++nf) {
                    int j = jw*64 + nf*16 + li;
                    if (j < 160) P[i][j] = bfrne(eacc[mf2][nf][r] * scale);
                }
            }
    }
    __syncthreads();

    // ================= phase PV + fused reduce =================
    {
        const int pc = w & 7, pi = w >> 3;
        f32x4 oacc[5];
        #pragma unroll
        for (int i = 0; i < 5; ++i) oacc[i] = f32x4{0.f,0.f,0.f,0.f};
        #pragma unroll
        for (int ks = 0; ks < 5; ++ks) {
            int c = pc*16 + li;
            int j0 = ks*32 + gq*8;
            U8 t;
            #pragma unroll
            for (int e = 0; e < 8; ++e) t.u[e] = vh[j0 + e][c];
            #pragma unroll
            for (int nf2 = 0; nf2 < 5; ++nf2) {
                int ir = pi*80 + nf2*16 + li;
                s16x8 bp = ld8l(&P[ir][ks*32 + gq*8]);
                oacc[nf2] = MFMA(t.v, bp, oacc[nf2]);
            }
        }

        float* pmax = mg;   // [2][128] (mg/sg dead)
        float* pdot = sg;
        #pragma unroll
        for (int r = 0; r < 4; ++r) {
            int c = pc*16 + gq*4 + r;
            float mx = -3.4e38f, dt = 0.f;
            #pragma unroll
            for (int nf2 = 0; nf2 < 5; ++nf2) {
                int l = pi*80 + nf2*16 + li;
                if (l < 150) {
                    float val = gamma * oacc[nf2][r];
                    mx = fmaxf(mx, val);
                    dt = fmaf(val, Wd[c*150 + l], dt);
                }
            }
            #pragma unroll
            for (int o = 1; o < 16; o <<= 1) {
                mx = fmaxf(mx, __shfl_xor(mx, o));
                dt += __shfl_xor(dt, o);
            }
            if (li == 0) { pmax[pi*128 + c] = mx; pdot[pi*128 + c] = dt; }
        }
        __syncthreads();
        if (tid < 128) {
            out[(long)b*512 + 256 + tid] = fmaxf(pmax[tid], pmax[128 + tid]);
            dw[b*256 + tid] = pdot[tid] + pdot[128 + tid];
        } else if (tid >= 256 && tid < 768) {   // v part (ch 128..255): 4 threads/channel
            int t2 = tid - 256, c2 = t2 >> 2, q3 = t2 & 3;
            int l0 = (q3*150) >> 2, l1 = ((q3 + 1)*150) >> 2;
            float mx = -3.4e38f, dt = 0.f;
            for (int l = l0; l < l1; ++l) {
                float val = bff(vh[l][c2]);
                mx = fmaxf(mx, val);
                dt = fmaf(val, Wd[(128 + c2)*150 + l], dt);
            }
            mx = fmaxf(mx, __shfl_xor(mx, 1));
            dt += __shfl_xor(dt, 1);
            mx = fmaxf(mx, __shfl_xor(mx, 2));
            dt += __shfl_xor(dt, 2);
            if (q3 == 0) {
                out[(long)b*512 + 256 + 128 + c2] = mx;
                dw[b*256 + 128 + c2] = dt;
            }
        }
    }
}

// ------------------------- tail: pw GEMM + BN (batch stats) + relu -------------------------
__global__ __launch_bounds__(256)
void tail_pwbn(const float* __restrict__ dw, const float* __restrict__ Wp,
               const float* __restrict__ bn_g, const float* __restrict__ bn_b,
               float* __restrict__ out)
{
    __shared__ float wp_s[256];
    __shared__ float rs[4], rs2[4];
    const int o = blockIdx.x, t = threadIdx.x;
    const int lane = t & 63, w = t >> 6;
    wp_s[t] = Wp[o * 256 + t];
    __syncthreads();
    const float4* dr = (const float4*)(dw + (long)t * 256);
    float acc = 0.f;
    #pragma unroll 8
    for (int i = 0; i < 64; ++i) {
        float4 d4 = dr[i];
        acc = fmaf(d4.x, wp_s[i*4+0], acc);
        acc = fmaf(d4.y, wp_s[i*4+1], acc);
        acc = fmaf(d4.z, wp_s[i*4+2], acc);
        acc = fmaf(d4.w, wp_s[i*4+3], acc);
    }
    float s = acc, s2 = acc * acc;
    #pragma unroll
    for (int d = 1; d < 64; d <<= 1) { s += __shfl_xor(s, d); s2 += __shfl_xor(s2, d); }
    if (lane == 0) { rs[w] = s; rs2[w] = s2; }
    __syncthreads();
    float S  = rs[0] + rs[1] + rs[2] + rs[3];
    float S2 = rs2[0] + rs2[1] + rs2[2] + rs2[3];
    float mean = S * (1.f/256.f);
    float var  = S2 * (1.f/256.f) - mean * mean;
    float sc = rsqrtf(var + 1e-5f) * bn_g[o];
    float sh = bn_b[o] - mean * sc;
    out[(long)t * 512 + o] = fmaxf(fmaf(acc, sc, sh), 0.f);
}

extern "C" void kernel_launch(void* const* d_in, const int* in_sizes, int n_in,
                              void* d_out, int out_size, void* d_ws, size_t ws_size,
                              hipStream_t stream)
{
    (void)in_sizes; (void)n_in; (void)out_size; (void)ws_size;
    const float* x    = (const float*)d_in[0];
    const float* Wv   = (const float*)d_in[1];
    const float* bv   = (const float*)d_in[2];
    const float* Wq   = (const float*)d_in[3];
    const float* bq   = (const float*)d_in[4];
    const float* Wk   = (const float*)d_in[5];
    const float* bk   = (const float*)d_in[6];  (void)bk; // row-const: cancels in softmax
    const float* gam  = (const float*)d_in[7];
    const float* Wd   = (const float*)d_in[8];
    // d_in[9] = bd, d_in[11] = bp: BN-invariant, unused.
    const float* Wp   = (const float*)d_in[10];
    const float* bn_g = (const float*)d_in[12];
    const float* bn_b = (const float*)d_in[13];
    float* out = (float*)d_out;

    char* wsb = (char*)d_ws;
    BF* wvh  = (BF*)wsb;                       // 131072
    BF* wvl  = (BF*)(wsb + 131072);            // 131072
    BF* wqh  = (BF*)(wsb + 262144);            // 32768
    BF* wql  = (BF*)(wsb + 294912);            // 32768
    float* cvec = (float*)(wsb + 327680);      // 512
    float* dw   = (float*)(wsb + 328192);      // 262144

    prep_all<<<81, 256, 0, stream>>>(Wv, Wq, Wk, bq, wvh, wvl, wqh, wql, cvec);
    fused_attn<<<256, 1024, 0, stream>>>(x, wvh, wvl, bv, wqh, wql, cvec,
                                         gam, Wd, dw, out);
    tail_pwbn<<<256, 256, 0, stream>>>(dw, Wp, bn_g, bn_b, out);
}